// Round 9
// baseline (84.979 us; speedup 1.0000x reference)
//
#include <hip/hip_runtime.h>
#include <hip/hip_bf16.h>
#include <math.h>

#define HW_   65536
#define B_    2
#define Q_    100
#define C_    134
#define T_    20
#define NHUN  100
#define MT_   7            // M-tiles of 16 queries (112 >= 100)
#define KSB   128          // K-split blocks per (b,mt)
#define BKCH  512          // k per block
#define PREC  1088         // part record stride (1024 frag + 16 F + 16 P + pad)
#define NCH   2048         // 32-k chunks per batch row (65536/32)

typedef __attribute__((ext_vector_type(8))) short bf16x8;
typedef __attribute__((ext_vector_type(4))) float f32x4;

// ws layout (float units)
#define LABPS_OFF  0                    // [2][20][8]
#define CC_OFF     512                  // [200][20] (fallback path only)
#define COST_OFF   4608                 // [200][20]
#define BASE_END   8704
#define LABF1_F   BASE_END                          // 2*2048*64*8 ushort = 1,048,576 floats
#define LABF2_F   (LABF1_F + 1048576)
#define PART_OFF  (LABF2_F + 1048576)               // 1792 records * 1088 floats
#define CSUM_OFF  (PART_OFF + B_ * KSB * MT_ * PREC)
#define WS_END_F  (CSUM_OFF + B_ * MT_ * 1056)

__device__ inline unsigned short f2bf(float f) {
    unsigned int u = __builtin_bit_cast(unsigned int, f);
    u += 0x7FFFu + ((u >> 16) & 1u);               // RNE
    return (unsigned short)(u >> 16);
}
__device__ inline float softplusf(float x) {
    float ax = fabsf(x);
    return fmaxf(x, 0.0f) + log1pf(expf(-ax));
}

// ---------------- K1: decimate labels -> fragment-ordered bf16 labF1/labF2 + row sums ----------------
// labF[b][chunk c][lane][e]: lane = t(&15) + 16*g holds row t, k = c*32 + g*8 + e.
__global__ void lab_prep_kernel(const float* __restrict__ ml, unsigned short* __restrict__ labF1,
                                unsigned short* __restrict__ labF2, float* __restrict__ lab_ps,
                                int writeT) {
    int b = blockIdx.x, t = blockIdx.y, ksl = blockIdx.z;
    int tid = threadIdx.x;
    const float* src = ml + (size_t)(b * T_ + t) * 262144;
    float acc = 0.f;
    for (int it = 0; it < 8; ++it) {
        int k = ksl * 8192 + it * 1024 + tid * 4;
        int r = k >> 8, c = k & 255;
        const float* s = src + r * 1024 + 2 * c;
        float4 u = *(const float4*)s;
        float4 w = *(const float4*)(s + 4);
        float v[4] = {u.x, u.z, w.x, w.z};
        unsigned short h[4];
#pragma unroll
        for (int e = 0; e < 4; ++e) { h[e] = f2bf(v[e]); acc += v[e]; }
        if (writeT) {
            int ch = k >> 5;            // 32-k chunk
            int g  = (k >> 3) & 3;      // k-group within chunk
            int e0 = k & 7;             // 0 or 4
            uint2 val;
            val.x = (unsigned)h[0] | ((unsigned)h[1] << 16);
            val.y = (unsigned)h[2] | ((unsigned)h[3] << 16);
            if (t < 16) {
                *(uint2*)(labF1 + ((size_t)(b * NCH + ch) * 64 + t + 16 * g) * 8 + e0) = val;
            } else {
                int lr = t - 16;
                *(uint2*)(labF2 + ((size_t)(b * NCH + ch) * 64 + lr + 16 * g) * 8 + e0) = val;
                uint2 z = {0u, 0u};
#pragma unroll
                for (int m = 1; m <= 3; ++m)
                    *(uint2*)(labF2 + ((size_t)(b * NCH + ch) * 64 + (lr + 4 * m) + 16 * g) * 8 + e0) = z;
            }
        }
    }
    for (int off = 32; off > 0; off >>= 1) acc += __shfl_down(acc, off);
    __shared__ float sb[4];
    int wid = tid >> 6, lane = tid & 63;
    if (lane == 0) sb[wid] = acc;
    __syncthreads();
    if (tid == 0) lab_ps[(b * T_ + t) * 8 + ksl] = sb[0] + sb[1] + sb[2] + sb[3];
}

// ---------------- class cost (fallback path only) ----------------
__global__ void class_cost_kernel(const float* __restrict__ cl, const int* __restrict__ labels,
                                  float* __restrict__ cc) {
    int bq  = blockIdx.x;
    int b   = bq / Q_;
    int tid = threadIdx.x;         // 64
    __shared__ float sl[C_];
    const float* src = cl + (size_t)bq * C_;
    for (int c = tid; c < C_; c += 64) sl[c] = src[c];
    __syncthreads();
    float mx = -INFINITY;
    for (int c = tid; c < C_; c += 64) mx = fmaxf(mx, sl[c]);
    for (int off = 32; off > 0; off >>= 1) mx = fmaxf(mx, __shfl_xor(mx, off));
    float se = 0.f;
    for (int c = tid; c < C_; c += 64) se += expf(sl[c] - mx);
    for (int off = 32; off > 0; off >>= 1) se += __shfl_xor(se, off);
    float inv = 1.0f / se;
    if (tid < T_) {
        int lbl = labels[b * T_ + tid];
        cc[bq * T_ + tid] = -expf(sl[lbl] - mx) * inv;
    }
}

// ---------------- K3: coalesced pointwise -> LDS (swizzled) -> MFMA partials ----------------
// blockIdx.x = (b*KSB + ks)*MT_ + mt ; 256 thr (4 waves)
// LDS: dh tile [16][512] bf16 @0, ph tile @16384; 16B-block swizzle blk^=(row&7).
__global__ __launch_bounds__(256) void focal_mfma_kernel(
        const float* __restrict__ mq, const unsigned short* __restrict__ labF1,
        const unsigned short* __restrict__ labF2, float* __restrict__ part) {
    int idx = blockIdx.x;
    int mt  = idx % MT_;
    int rem = idx / MT_;
    int ks  = rem % KSB;
    int b   = rem / KSB;
    int tid  = threadIdx.x;
    int wave = tid >> 6, lane = tid & 63;
    int lr = lane & 15, lg = lane >> 4;

    __shared__ char smem[33344];           // 32KB tiles; red/fpb reuse after barrier

    // ---- pointwise phase: linear layout, coalesced mq reads ----
    int grp = tid >> 7;                    // 0/1 (wave>>1)
    int kk4 = (tid & 127) * 4;             // k within tile, multiple of 4
    float Fa[8], Pa[8];
#pragma unroll
    for (int p = 0; p < 8; ++p) {
        int r = p * 2 + grp;               // tile row 0..15
        int q = mt * 16 + r;
        const float* xr = mq + ((size_t)(b * Q_ + (q < Q_ ? q : 0)) << 16) + ks * BKCH + kk4;
        float4 xv = *(const float4*)xr;
        unsigned short dh[4], ph[4];
        float Fs = 0.f, Ps = 0.f;
#pragma unroll
        for (int e = 0; e < 4; ++e) {
            float x  = (&xv.x)[e];
            float ax = fabsf(x);
            float a  = __expf(-ax);
            float rr = 1.0f / (1.0f + a);
            float p_ = (x >= 0.f) ? rr : a * rr;
            float om = (x >= 0.f) ? a * rr : rr;
            float l1 = __logf(1.0f + a);
            float spn = fmaxf(-x, 0.f) + l1;       // softplus(-x)
            float spp = spn + x;                   // softplus(x)
            float fp = 0.25f * om * om * spn;
            float fn = 0.75f * p_ * p_ * spp;
            Fs += fn; Ps += p_;
            dh[e] = f2bf(fp - fn);
            ph[e] = f2bf(p_);
        }
        Fa[p] = Fs; Pa[p] = Ps;
        // swizzled LDS write: byte = r*1024 + ((k>>3)^(r&7))*16 + (k&4)*2
        int wr = r * 1024 + ((((kk4 >> 3)) ^ (r & 7)) << 4) + ((kk4 & 4) << 1);
        uint2 dv, pv;
        dv.x = (unsigned)dh[0] | ((unsigned)dh[1] << 16);
        dv.y = (unsigned)dh[2] | ((unsigned)dh[3] << 16);
        pv.x = (unsigned)ph[0] | ((unsigned)ph[1] << 16);
        pv.y = (unsigned)ph[2] | ((unsigned)ph[3] << 16);
        *(uint2*)(smem + wr)         = dv;
        *(uint2*)(smem + 16384 + wr) = pv;
    }
    __syncthreads();

    // ---- MFMA phase: swizzled ds_read + coalesced labF loads ----
    f32x4 accD0 = {0,0,0,0}, accD1 = {0,0,0,0};
    f32x4 accP0 = {0,0,0,0}, accP1 = {0,0,0,0};
#pragma unroll
    for (int kk = 0; kk < 4; ++kk) {
        int blk = wave * 16 + kk * 4 + lg;                // 16B-block index
        int ad  = lr * 1024 + ((blk ^ (lr & 7)) << 4);
        bf16x8 adh = *(const bf16x8*)(smem + ad);
        bf16x8 aph = *(const bf16x8*)(smem + 16384 + ad);
        int c = ks * (BKCH / 32) + wave * 4 + kk;
        const unsigned short* f1p = labF1 + ((size_t)(b * NCH + c) * 64 + lane) * 8;
        const unsigned short* f2p = labF2 + ((size_t)(b * NCH + c) * 64 + lane) * 8;
        bf16x8 f1 = *(const bf16x8*)f1p;
        bf16x8 f2 = *(const bf16x8*)f2p;
        accD0 = __builtin_amdgcn_mfma_f32_16x16x32_bf16(adh, f1, accD0, 0, 0, 0);
        accD1 = __builtin_amdgcn_mfma_f32_16x16x32_bf16(adh, f2, accD1, 0, 0, 0);
        accP0 = __builtin_amdgcn_mfma_f32_16x16x32_bf16(aph, f1, accP0, 0, 0, 0);
        accP1 = __builtin_amdgcn_mfma_f32_16x16x32_bf16(aph, f2, accP1, 0, 0, 0);
    }
    __syncthreads();     // tiles dead; reuse smem for reductions

    float (*red)[4][64][4] = (float (*)[4][64][4])smem;      // 16 KB @0
    float (*wfpF)[8] = (float (*)[8])(smem + 16384);         // [4][8]
    float (*wfpP)[8] = (float (*)[8])(smem + 16384 + 128);   // [4][8]
#pragma unroll
    for (int r = 0; r < 4; ++r) {
        red[wave][0][lane][r] = accD0[r];
        red[wave][1][lane][r] = accD1[r];
        red[wave][2][lane][r] = accP0[r];
        red[wave][3][lane][r] = accP1[r];
    }
#pragma unroll
    for (int p = 0; p < 8; ++p) {
        float f = Fa[p], pp = Pa[p];
        for (int off = 32; off > 0; off >>= 1) {
            f  += __shfl_down(f, off);
            pp += __shfl_down(pp, off);
        }
        if (lane == 0) { wfpF[wave][p] = f; wfpP[wave][p] = pp; }
    }
    __syncthreads();
    for (int e = tid; e < 1024; e += 256) {
        int f  = e >> 8;
        int l2 = (e & 255) >> 2;
        int r  = e & 3;
        part[(size_t)idx * PREC + e] =
            red[0][f][l2][r] + red[1][f][l2][r] + red[2][f][l2][r] + red[3][f][l2][r];
    }
    if (tid < 16) {
        int p = tid >> 1, g = tid & 1;
        part[(size_t)idx * PREC + 1024 + tid] = wfpF[2 * g][p] + wfpF[2 * g + 1][p];
        part[(size_t)idx * PREC + 1040 + tid] = wfpP[2 * g][p] + wfpP[2 * g + 1][p];
    }
}

// ---------------- K4a: parallel K-split reduction: part -> Csum[14][1056] ----------------
__global__ __launch_bounds__(256) void reduce_part_kernel(const float* __restrict__ part,
                                                          float* __restrict__ Csum) {
    int bm   = blockIdx.x;          // 0..13
    int mt   = bm % MT_;
    int b    = bm / MT_;
    int tid  = threadIdx.x;
    int epos = tid & 31;
    int grp  = tid >> 5;            // 0..7
    int e    = blockIdx.y * 32 + epos;   // 0..1055

    const float* base = part + (size_t)((b * KSB) * MT_ + mt) * PREC + e;
    float s = 0.f;
    for (int k = 0; k < 16; ++k) {
        s += base[(size_t)(grp * 16 + k) * MT_ * PREC];
    }
    __shared__ float red[8][33];
    red[grp][epos] = s;
    __syncthreads();
    if (tid < 32) {
        float tot = 0.f;
        for (int g = 0; g < 8; ++g) tot += red[g][tid];
        Csum[(size_t)bm * 1056 + e] = tot;
    }
}

// ---------------- K4b: finalize cost from Csum + fused class-softmax ----------------
__global__ __launch_bounds__(320) void compose_kernel(
        const float* __restrict__ Csum, const float* __restrict__ cl,
        const int* __restrict__ labels, const float* __restrict__ lab_ps,
        float* __restrict__ cost) {
    int bm = blockIdx.x;
    int mt = bm % MT_;
    int b  = bm / MT_;
    int tid = threadIdx.x;     // 320
    int q0 = mt * 16;

    __shared__ float sl[16][136];
    __shared__ float mx[16], se[16];
    __shared__ int   lbl[T_];
    for (int e = tid; e < 16 * C_; e += 320) {
        int qm = e / C_, c = e % C_;
        int q = q0 + qm;
        sl[qm][c] = (q < Q_) ? cl[(size_t)(b * Q_ + q) * C_ + c] : 0.f;
    }
    if (tid < T_) lbl[tid] = labels[b * T_ + tid];
    __syncthreads();
    if (tid < 16) {
        float m = -INFINITY;
        for (int c = 0; c < C_; ++c) m = fmaxf(m, sl[tid][c]);
        float s = 0.f;
        for (int c = 0; c < C_; ++c) s += expf(sl[tid][c] - m);
        mx[tid] = m; se[tid] = s;
    }
    __syncthreads();

    int qm = tid / T_, t = tid % T_;
    int q = q0 + qm;
    if (qm < 16 && q < Q_) {
        const float* C = Csum + (size_t)bm * 1056;
        int nt   = t >> 4;
        int lane = ((qm >> 2) << 4) | (t & 15);
        int reg  = qm & 3;
        float Sd = C[(0 + nt) * 256 + lane * 4 + reg];
        float Sp = C[(2 + nt) * 256 + lane * 4 + reg];
        float F  = C[1024 + qm];
        float P  = C[1040 + qm];
        float L = 0.f;
        for (int s8 = 0; s8 < 8; ++s8) L += lab_ps[(b * T_ + t) * 8 + s8];
        float ccv = -expf(sl[qm][lbl[t]] - mx[qm]) / se[qm];
        float cm = (Sd + F) * (1.0f / (float)HW_);
        float cd = 1.0f - (2.0f * Sp + 1.0f) / (P + L + 1.0f);
        cost[(size_t)(b * Q_ + q) * T_ + t] = cm + cd + ccv;
    }
}

// ---------------- fallback: monolithic (round-2 proven) ----------------
__global__ __launch_bounds__(1024) void mask_cost_mono_kernel(
        const float* __restrict__ mq, const float* __restrict__ ml,
        const float* __restrict__ cc, const float* __restrict__ lab_ps,
        float* __restrict__ cost) {
    int bq  = blockIdx.x;
    int b   = bq / Q_;
    int tid = threadIdx.x;
    const float* xb  = mq + (size_t)bq * HW_;
    const float* mlb = ml + (size_t)b * T_ * 262144;
    float s1[T_], s2[T_];
#pragma unroll
    for (int t = 0; t < T_; ++t) { s1[t] = 0.f; s2[t] = 0.f; }
    float F = 0.f, P = 0.f;
    for (int k = tid; k < HW_; k += 1024) {
        int i = k >> 8, j = k & 255;
        float x = xb[k];
        float p = 1.0f / (1.0f + expf(-x));
        float spn = softplusf(-x);
        float spp = softplusf(x);
        float om = 1.0f - p;
        float fp = 0.25f * om * om * spn;
        float fn = 0.75f * p * p * spp;
        F += fn; P += p;
        float diff = fp - fn;
        int off0 = i * 1024 + 2 * j;
#pragma unroll
        for (int t = 0; t < T_; ++t) {
            float lab = mlb[t * 262144 + off0];
            s1[t] = fmaf(diff, lab, s1[t]);
            s2[t] = fmaf(p,    lab, s2[t]);
        }
    }
    __shared__ float sbuf[16][42];
    int wid = tid >> 6, lane = tid & 63;
#pragma unroll
    for (int t = 0; t < T_; ++t) {
        for (int off = 32; off > 0; off >>= 1) {
            s1[t] += __shfl_down(s1[t], off);
            s2[t] += __shfl_down(s2[t], off);
        }
    }
    for (int off = 32; off > 0; off >>= 1) { F += __shfl_down(F, off); P += __shfl_down(P, off); }
    if (lane == 0) {
#pragma unroll
        for (int t = 0; t < T_; ++t) { sbuf[wid][t] = s1[t]; sbuf[wid][T_ + t] = s2[t]; }
        sbuf[wid][40] = F; sbuf[wid][41] = P;
    }
    __syncthreads();
    if (tid < T_) {
        float S1 = 0.f, S2 = 0.f, Fs = 0.f, Ps = 0.f;
        for (int w = 0; w < 16; ++w) {
            S1 += sbuf[w][tid]; S2 += sbuf[w][T_ + tid];
            Fs += sbuf[w][40];  Ps += sbuf[w][41];
        }
        float L = 0.f;
        for (int sl = 0; sl < 8; ++sl) L += lab_ps[(b * T_ + tid) * 8 + sl];
        float cm = (S1 + Fs) * (1.0f / (float)HW_);
        float cd = 1.0f - (2.0f * S2 + 1.0f) / (Ps + L + 1.0f);
        cost[bq * T_ + tid] = cm + cd + cc[bq * T_ + tid];
    }
}

// ---------------- K5: transposed rectangular JV Hungarian, one wave, float + ballot-argmin ----------------
__global__ __launch_bounds__(64) void hungarian_kernel(const float* __restrict__ cost,
                                                       int* __restrict__ out) {
    int b    = blockIdx.x;
    int lane = threadIdx.x;

    __shared__ float csh[Q_ * T_];
    __shared__ float u[T_ + 1];
    __shared__ int   p[NHUN + 1];
    __shared__ int   way[NHUN + 1];

    for (int idx = lane; idx < Q_ * T_; idx += 64) csh[idx] = cost[b * Q_ * T_ + idx];
    for (int j = lane; j <= NHUN; j += 64) { p[j] = 0; way[j] = 0; }
    if (lane <= T_) u[lane] = 0.f;
    __syncthreads();

    const int ja = lane;            // column A (0 = virtual root on lane 0)
    const int jb = lane + 64;       // column B (valid up to 100)
    const bool jb_ok = (jb <= NHUN);
    float v_a = 0.f, v_b = 0.f;

    for (int i = 1; i <= T_; ++i) {
        if (lane == 0) p[0] = i;
        float m_a = INFINITY, m_b = INFINITY;
        bool us_a = false, us_b = false;
        __syncthreads();
        int j0 = 0;
        while (true) {
            if (ja == j0) us_a = true;
            if (jb == j0) us_b = true;
            int   i0  = p[j0];
            float ui0 = u[i0];
            bool fa = (!us_a && ja >= 1);
            bool fb = (jb_ok && !us_b);
            if (fa) {
                float cur = csh[(ja - 1) * T_ + (i0 - 1)] - ui0 - v_a;
                if (cur < m_a) { m_a = cur; way[ja] = j0; }
            }
            if (fb) {
                float cur = csh[(jb - 1) * T_ + (i0 - 1)] - ui0 - v_b;
                if (cur < m_b) { m_b = cur; way[jb] = j0; }
            }
            float ca = fa ? m_a : INFINITY;
            float cb = fb ? m_b : INFINITY;
            float vmin = fminf(ca, cb);
            for (int off = 32; off > 0; off >>= 1)
                vmin = fminf(vmin, __shfl_xor(vmin, off));
            unsigned long long ba = __ballot(ca == vmin);
            int j1;
            if (ba) j1 = __ffsll(ba) - 1;
            else    j1 = __ffsll(__ballot(cb == vmin)) - 1 + 64;
            float delta = vmin;
            if (us_a) { u[p[ja]] += delta; v_a -= delta; } else { m_a -= delta; }
            if (jb_ok) {
                if (us_b) { u[p[jb]] += delta; v_b -= delta; } else { m_b -= delta; }
            }
            __threadfence_block();
            j0 = j1;
            if (p[j0] == 0) break;
        }
        if (lane == 0) {
            int jj = j0;
            while (jj) { int jn = way[jj]; p[jj] = p[jn]; jj = jn; }
        }
        __syncthreads();
    }

    if (lane == 0) {
        int* ob = out + b * 2 * T_;
        int k = 0;
        for (int j = 1; j <= NHUN; ++j) {
            if (p[j] != 0) { ob[k] = j - 1; ob[T_ + k] = p[j] - 1; ++k; }
        }
    }
}

extern "C" void kernel_launch(void* const* d_in, const int* in_sizes, int n_in,
                              void* d_out, int out_size, void* d_ws, size_t ws_size,
                              hipStream_t stream) {
    const float* mq     = (const float*)d_in[0];   // [2,100,256,256]
    const float* cl     = (const float*)d_in[1];   // [2,100,134]
    const float* ml     = (const float*)d_in[2];   // [2,20,512,512]
    const int*   labels = (const int*)d_in[3];     // [2,20]
    int* out = (int*)d_out;                        // [2,2,20] int32
    float* ws = (float*)d_ws;

    float* lab_ps = ws + LABPS_OFF;
    float* cc     = ws + CC_OFF;
    float* cost   = ws + COST_OFF;

    size_t need = (size_t)WS_END_F * 4;

    if (ws_size >= need) {
        unsigned short* labF1 = (unsigned short*)(ws + LABF1_F);
        unsigned short* labF2 = (unsigned short*)(ws + LABF2_F);
        float* part = ws + PART_OFF;
        float* Csum = ws + CSUM_OFF;
        hipLaunchKernelGGL(lab_prep_kernel,   dim3(B_, T_, 8), dim3(256), 0, stream,
                           ml, labF1, labF2, lab_ps, 1);
        hipLaunchKernelGGL(focal_mfma_kernel, dim3(B_ * KSB * MT_), dim3(256), 0, stream,
                           mq, labF1, labF2, part);
        hipLaunchKernelGGL(reduce_part_kernel, dim3(B_ * MT_, 33), dim3(256), 0, stream,
                           part, Csum);
        hipLaunchKernelGGL(compose_kernel,    dim3(B_ * MT_),  dim3(320), 0, stream,
                           Csum, cl, labels, lab_ps, cost);
    } else {
        hipLaunchKernelGGL(lab_prep_kernel,   dim3(B_, T_, 8), dim3(256), 0, stream,
                           ml, (unsigned short*)ws, (unsigned short*)ws, lab_ps, 0);
        hipLaunchKernelGGL(class_cost_kernel, dim3(B_ * Q_),   dim3(64),  0, stream, cl, labels, cc);
        hipLaunchKernelGGL(mask_cost_mono_kernel, dim3(B_ * Q_), dim3(1024), 0, stream,
                           mq, ml, cc, lab_ps, cost);
    }
    hipLaunchKernelGGL(hungarian_kernel, dim3(B_), dim3(64), 0, stream, cost, out);
}